// Round 18
// baseline (2012.761 us; speedup 1.0000x reference)
//
#include <hip/hip_runtime.h>

// ---------------------------------------------------------------------------
// Problem constants: B=2, L=1024, D=1024, H=16, DK=DV=64
// ---------------------------------------------------------------------------

typedef unsigned short u16;
typedef u16  u16x4 __attribute__((ext_vector_type(4)));
typedef short bf16x8 __attribute__((ext_vector_type(8)));
typedef float f32x4 __attribute__((ext_vector_type(4)));

struct MSlot { const u16* Wh; const u16* Wl; const float* bias; float* out; int mode; };
struct MBatch { MSlot s[4]; };
struct WSplitSlot { const float* W; u16* Th; u16* Tl; };
struct WSplitBatch { WSplitSlot s[5]; };

__device__ __forceinline__ float silu_(float x) {
  return x / (1.f + __expf(-x));
}
__device__ __forceinline__ float sigm_(float x) {
  return 1.f / (1.f + __expf(-x));
}
__device__ __forceinline__ float rdl_(float v, int l) {
  return __int_as_float(__builtin_amdgcn_readlane(__float_as_int(v), l));
}
// round-to-nearest-even bf16 split: x ~= hi + lo (each bf16), err ~ x*2^-17
__device__ __forceinline__ void split2_(float x, u16& h, u16& l) {
  unsigned u = __float_as_uint(x);
  unsigned r = (u + 0x7FFFu + ((u >> 16) & 1u)) >> 16;
  h = (u16)r;
  float lo = x - __uint_as_float(r << 16);
  unsigned u2 = __float_as_uint(lo);
  unsigned r2 = (u2 + 0x7FFFu + ((u2 >> 16) & 1u)) >> 16;
  l = (u16)r2;
}

// ---------------------------------------------------------------------------
// split_mk: X[n] f32 -> H[n], L[n] bf16 (hi/lo), float4-vectorized.
// ---------------------------------------------------------------------------
__global__ __launch_bounds__(256) void split_mk(
    const float* __restrict__ X, u16* __restrict__ H, u16* __restrict__ L, int n4)
{
  int i = blockIdx.x * 256 + threadIdx.x;
  if (i >= n4) return;
  float4 x = ((const float4*)X)[i];
  u16 h0, h1, h2, h3, l0, l1, l2, l3;
  split2_(x.x, h0, l0);
  split2_(x.y, h1, l1);
  split2_(x.z, h2, l2);
  split2_(x.w, h3, l3);
  u16x4 h, l;
  h.x = h0; h.y = h1; h.z = h2; h.w = h3;
  l.x = l0; l.y = l1; l.z = l2; l.w = l3;
  ((u16x4*)H)[i] = h;
  ((u16x4*)L)[i] = l;
}

// ---------------------------------------------------------------------------
// splitT: W[1024][1024] f32 -> Th[N][K], Tl[N][K] bf16 (transposed + split).
// ---------------------------------------------------------------------------
__global__ __launch_bounds__(256) void splitT(WSplitBatch wb)
{
  const WSplitSlot sl = wb.s[blockIdx.z];
  __shared__ float tl[32][33];
  const int tid = threadIdx.x;
  const int k0 = blockIdx.x * 32, n0 = blockIdx.y * 32;
  const int c = tid & 31, r8 = tid >> 5;
#pragma unroll
  for (int j = 0; j < 4; ++j) {
    int r = r8 + 8 * j;
    tl[r][c] = sl.W[(size_t)(k0 + r) * 1024 + n0 + c];
  }
  __syncthreads();
#pragma unroll
  for (int j = 0; j < 4; ++j) {
    int nr = r8 + 8 * j;
    float x = tl[c][nr];
    u16 h, l;
    split2_(x, h, l);
    sl.Th[(size_t)(n0 + nr) * 1024 + k0 + c] = h;
    sl.Tl[(size_t)(n0 + nr) * 1024 + k0 + c] = l;
  }
}

// ---------------------------------------------------------------------------
// Split-bf16 MFMA GEMM (r17, passed): register double-buffered fragments.
// ---------------------------------------------------------------------------
__global__ __launch_bounds__(256) void gemm_mfma(
    const u16* __restrict__ Ah, const u16* __restrict__ Al,
    MBatch gb, int M, int N, int K)
{
  const MSlot sl = gb.s[blockIdx.z];
  const int tid = threadIdx.x;
  const int w = tid >> 6, lane = tid & 63;
  const int fm = lane & 15, kg = lane >> 4;
  const int bm = blockIdx.x * 128, bn = blockIdx.y * 64;

  const size_t arow = (size_t)(bm + 32 * w + fm) * K + kg * 8;
  const u16* pa0h = Ah + arow;
  const u16* pa1h = pa0h + 16 * K;
  const u16* pa0l = Al + arow;
  const u16* pa1l = pa0l + 16 * K;
  const size_t brow = (size_t)(bn + fm) * K + kg * 8;
  const u16* pbh = sl.Wh + brow;
  const u16* pbl = sl.Wl + brow;

  f32x4 acc[2][4];
#pragma unroll
  for (int i = 0; i < 2; ++i)
#pragma unroll
    for (int j = 0; j < 4; ++j) acc[i][j] = (f32x4)(0.f);

  bf16x8 a0h = *(const bf16x8*)(pa0h);
  bf16x8 a1h = *(const bf16x8*)(pa1h);
  bf16x8 a0l = *(const bf16x8*)(pa0l);
  bf16x8 a1l = *(const bf16x8*)(pa1l);
  bf16x8 bh[4], bl[4];
#pragma unroll
  for (int c = 0; c < 4; ++c) {
    bh[c] = *(const bf16x8*)(pbh + (size_t)16 * c * K);
    bl[c] = *(const bf16x8*)(pbl + (size_t)16 * c * K);
  }

  for (int ko = 0; ko < K; ko += 32) {
    bf16x8 na0h, na1h, na0l, na1l, nbh[4], nbl[4];
    const int kn = ko + 32;
    if (kn < K) {
      na0h = *(const bf16x8*)(pa0h + kn);
      na1h = *(const bf16x8*)(pa1h + kn);
      na0l = *(const bf16x8*)(pa0l + kn);
      na1l = *(const bf16x8*)(pa1l + kn);
#pragma unroll
      for (int c = 0; c < 4; ++c) {
        nbh[c] = *(const bf16x8*)(pbh + (size_t)16 * c * K + kn);
        nbl[c] = *(const bf16x8*)(pbl + (size_t)16 * c * K + kn);
      }
    }
#pragma unroll
    for (int c = 0; c < 4; ++c) {
      acc[0][c] = __builtin_amdgcn_mfma_f32_16x16x32_bf16(a0h, bh[c], acc[0][c], 0, 0, 0);
      acc[0][c] = __builtin_amdgcn_mfma_f32_16x16x32_bf16(a0l, bh[c], acc[0][c], 0, 0, 0);
      acc[0][c] = __builtin_amdgcn_mfma_f32_16x16x32_bf16(a0h, bl[c], acc[0][c], 0, 0, 0);
      acc[1][c] = __builtin_amdgcn_mfma_f32_16x16x32_bf16(a1h, bh[c], acc[1][c], 0, 0, 0);
      acc[1][c] = __builtin_amdgcn_mfma_f32_16x16x32_bf16(a1l, bh[c], acc[1][c], 0, 0, 0);
      acc[1][c] = __builtin_amdgcn_mfma_f32_16x16x32_bf16(a1h, bl[c], acc[1][c], 0, 0, 0);
    }
    if (kn < K) {
      a0h = na0h; a1h = na1h; a0l = na0l; a1l = na1l;
#pragma unroll
      for (int c = 0; c < 4; ++c) { bh[c] = nbh[c]; bl[c] = nbl[c]; }
    }
  }

  const float* bias = sl.bias;
  float* out = sl.out;
  const int mode = sl.mode;
#pragma unroll
  for (int rt = 0; rt < 2; ++rt) {
#pragma unroll
    for (int c = 0; c < 4; ++c) {
      f32x4 v = acc[rt][c];
      const int n = bn + 16 * c + fm;
      const float bsv = bias[n];
#pragma unroll
      for (int r = 0; r < 4; ++r) {
        int m = bm + 32 * w + 16 * rt + kg * 4 + r;
        float cc = v[r] + bsv;
        if (mode >= 1) cc = silu_(cc);
        if (mode == 2) {
          int h = n >> 6, d = n & 63;
          int b = m >> 10, l = m & 1023;
          out[(((size_t)(b * 16 + h)) * 1024 + l) * 64 + d] = cc;
        } else {
          out[(size_t)m * N + n] = cc;
        }
      }
    }
  }
}

// ---------------------------------------------------------------------------
// Scalar projections: LDS-tiled (8 hs rows/block), packed scl[bh][t][8]
// ---------------------------------------------------------------------------
__global__ __launch_bounds__(256) void scalar_proj(
    const float* __restrict__ hs,
    const float* __restrict__ Wb,  const float* __restrict__ bb,
    const float* __restrict__ Wfd, const float* __restrict__ bfd, const float* __restrict__ fdb,
    const float* __restrict__ Wsd, const float* __restrict__ bsd, const float* __restrict__ sdb,
    const float* __restrict__ Wfg, const float* __restrict__ bfg,
    const float* __restrict__ Wsg, const float* __restrict__ bsg,
    float* __restrict__ scl)
{
  __shared__ float hl[8][1028];
  const int tid = threadIdx.x;
  const int m0 = blockIdx.x * 8;

#pragma unroll
  for (int i = 0; i < 8; ++i) {
    int f = tid + 256 * i;
    int r = f >> 8;
    int c4 = f & 255;
    float4 v = *(const float4*)&hs[(size_t)(m0 + r) * 1024 + c4 * 4];
    *(float4*)&hl[r][c4 * 4] = v;
  }
  __syncthreads();

  for (int c = 0; c < 3; ++c) {
    int o = tid + 256 * c;
    if (o >= 640) break;
    int ml = o / 80;
    int cc = o - ml * 80;
    int type = cc >> 4;
    int h = cc & 15;
    const float* W; const float* bias; float extra = 0.f;
    switch (type) {
      case 0:  W = Wb;  bias = bb;  break;
      case 1:  W = Wfd; bias = bfd; extra = fdb[h]; break;
      case 2:  W = Wsd; bias = bsd; extra = sdb[h]; break;
      case 3:  W = Wfg; bias = bfg; break;
      default: W = Wsg; bias = bsg; break;
    }
    float s = 0.f;
    for (int k = 0; k < 1024; k += 4) {
      float4 hv = *(const float4*)&hl[ml][k];
      s = fmaf(hv.x, W[(k + 0) * 16 + h], s);
      s = fmaf(hv.y, W[(k + 1) * 16 + h], s);
      s = fmaf(hv.z, W[(k + 2) * 16 + h], s);
      s = fmaf(hv.w, W[(k + 3) * 16 + h], s);
    }
    s += bias[h] + extra;
    int m = m0 + ml;
    int b = m >> 10, l = m & 1023;
    scl[((size_t)((b * 16 + h) * 1024 + l)) * 8 + type] = sigm_(s);
  }
}

// ---------------------------------------------------------------------------
// Pre-normalize q and k in place: x *= rsqrt(sum_64(x^2)+1e-6).
// ---------------------------------------------------------------------------
__global__ __launch_bounds__(256) void prenorm(float* __restrict__ p)
{
  int wid = blockIdx.x * 4 + (threadIdx.x >> 6);
  int lane = threadIdx.x & 63;
  size_t idx = (size_t)wid * 64 + lane;
  float x = p[idx];
  float ss = x * x;
#pragma unroll
  for (int d2 = 32; d2 >= 1; d2 >>= 1) ss += __shfl_xor(ss, d2, 64);
  p[idx] = x * rsqrtf(ss + 1e-6f);
}

// ---------------------------------------------------------------------------
// Sequential scan v14: TWO (b,h) groups per block (16 waves, 1024 threads,
// 16 blocks) -> 4 waves/SIMD. The r13 schedule (deferred cap, one raw
// barrier, wave-specialized reduces) is unchanged per group; the shared
// barrier couples the two symmetric groups (benign) while doubling the
// waves available to absorb shfl/LDS/readlane latency (r13 measured ~1800
// cyc/step exposed stall at 2 waves/SIMD).
// ---------------------------------------------------------------------------
__global__ __launch_bounds__(1024) void scan_kernel(
    const float* __restrict__ qg, const float* __restrict__ kg, const float* __restrict__ vg,
    const float* __restrict__ scl, const float* __restrict__ rfx, float* __restrict__ og)
{
  const int tid = threadIdx.x;
  const int lane = tid & 63;       // column index
  const int wid = tid >> 6;        // 0..15
  const int g = wid >> 3;          // group 0/1
  const int w = wid & 7;           // wave-in-group: rows [8w, 8w+8)
  const int bh = blockIdx.x * 2 + g;
  const float rf = rfx[0];
  const float rf2 = rf * rf;

  __shared__ float2 pE[2][2][8][64];  // [group][parity][wave][lane]
  __shared__ float2 pG[2][2][8][64];
  __shared__ float4 xb[2][2];         // [group][parity]

  float Sf[8], Ss[8];
#pragma unroll
  for (int j = 0; j < 8; ++j) { Sf[j] = 0.f; Ss[j] = 0.f; }

  const float* kb = kg + (size_t)bh * 65536;
  const float* qb = qg + (size_t)bh * 65536;
  const float* vb = vg + (size_t)bh * 65536;
  const float* sb = scl + (size_t)bh * 8192;
  const int b = bh >> 4, h = bh & 15;
  float* ob = og + (size_t)b * (1024 * 1024) + h * 64;

  float kv0 = kb[lane], qv0 = qb[lane];
  float kvA = kb[64 + lane], qvA = qb[64 + lane];
  float vv = vb[lane];
  float4 sc = *(const float4*)&sb[0];
  float sg4 = sb[4];

  float kr[8];
#pragma unroll
  for (int j = 0; j < 8; ++j) kr[j] = rdl_(kv0, w * 8 + j);

  float qkc = 0.f;
  if (w == 1) {
    float t0 = kv0 * qv0;
#pragma unroll
    for (int d2 = 32; d2 >= 1; d2 >>= 1) t0 += __shfl_xor(t0, d2, 64);
    qkc = t0;
  }

  float alf = 1.f, als = 1.f;
  float Nf = 0.f, Ns = 0.f, Cc = 0.f;
  float fdp = 1.f, sdp = 1.f;
  float fgp = 0.f, sgp = 0.f;
  float ofp = 0.f, osp = 0.f;
  float ef = 0.f, es = 0.f, gf = 0.f, gs = 0.f;

  for (int t = 0; t < 1024; ++t) {
    const int t1 = (t + 1) & 1023;
    const int t2 = (t + 2) & 1023;

    if (t > 0) {
      asm volatile("s_waitcnt lgkmcnt(0)" ::: "memory");
      __builtin_amdgcn_s_barrier();
    }

    const float kvB = kb[t2 * 64 + lane];
    const float qvB = qb[t2 * 64 + lane];
    const float vn  = vb[t1 * 64 + lane];
    const float4 scn = *(const float4*)&sb[(size_t)t1 * 8];
    const float sgn = sb[(size_t)t1 * 8 + 4];

    if (t > 0) {
      const int pr = (t - 1) & 1;
      float2 e0 = pE[g][pr][0][lane], e1 = pE[g][pr][1][lane];
      float2 e2 = pE[g][pr][2][lane], e3 = pE[g][pr][3][lane];
      float2 e4 = pE[g][pr][4][lane], e5 = pE[g][pr][5][lane];
      float2 e6 = pE[g][pr][6][lane], e7 = pE[g][pr][7][lane];
      float2 g0 = pG[g][pr][0][lane], g1 = pG[g][pr][1][lane];
      float2 g2 = pG[g][pr][2][lane], g3 = pG[g][pr][3][lane];
      float2 g4 = pG[g][pr][4][lane], g5 = pG[g][pr][5][lane];
      float2 g6 = pG[g][pr][6][lane], g7 = pG[g][pr][7][lane];
      ef = ((e0.x + e1.x) + (e2.x + e3.x)) + ((e4.x + e5.x) + (e6.x + e7.x));
      es = ((e0.y + e1.y) + (e2.y + e3.y)) + ((e4.y + e5.y) + (e6.y + e7.y));
      gf = ((g0.x + g1.x) + (g2.x + g3.x)) + ((g4.x + g5.x) + (g6.x + g7.x));
      gs = ((g0.y + g1.y) + (g2.y + g3.y)) + ((g4.y + g5.y) + (g6.y + g7.y));
      const float4 xv = xb[g][pr];
      const float Nfd = fmaf(fdp * fdp, Nf, xv.x);
      const float Nsd = fmaf(sdp * sdp, Ns, xv.y);
      const float Cd  = fmaf(fdp * sdp, Cc, xv.z);
      const float NTf = Nfd + 2.f * rf * Cd + rf2 * Nsd;
      const float NTs = Nsd + 2.f * rf * Cd + rf2 * Nfd;
      const float CT  = (1.f + rf2) * Cd + rf * (Nfd + Nsd);
      const bool capf = NTf > 4096.f;
      const bool caps = NTs > 4096.f;
      const float scf = capf ? 64.f * rsqrtf(NTf) : 1.f;
      const float scs = caps ? 64.f * rsqrtf(NTs) : 1.f;
      Nf = capf ? 4096.f : NTf;
      Ns = caps ? 4096.f : NTs;
      Cc = scf * scs * CT;
      alf *= scf; als *= scs;
      if (w == 1)
        ob[(size_t)(t - 1) * 1024 + lane] = fgp * alf * ofp + sgp * als * osp;
    }

    const float bt = sc.x, fdt = sc.y, sdt = sc.z, fgt = sc.w, sgt = sg4;

    const float d_f = alf * fdt, d_s = als * sdt;
    const float EF = d_f * ef, ES = d_s * es;
    const float errf = vv - EF, errs = vv - ES;
    const float rdf = 1.f / d_f, rds = 1.f / d_s;
    const float beff = bt * errf * rdf;
    const float bess = bt * errs * rds;
    const float cfs = rf * d_s * rdf;
    const float csf = rf * d_f * rds;

    float x1 = 0.f, x2 = 0.f, x3 = 0.f;
    if (w == 0) {
      x1 = bt * errf * fmaf(bt, errf, 2.f * EF);
      x2 = bt * errs * fmaf(bt, errs, 2.f * ES);
      x3 = bt * (fmaf(bt, errf * errs, errs * EF) + errf * ES);
#pragma unroll
      for (int d2 = 32; d2 >= 1; d2 >>= 1) {
        x1 += __shfl_xor(x1, d2, 64);
        x2 += __shfl_xor(x2, d2, 64);
        x3 += __shfl_xor(x3, d2, 64);
      }
    }

    float qkn = 0.f, of_new = 0.f, os_new = 0.f;
    if (w == 1) {
      float t0 = kvA * qvA;
#pragma unroll
      for (int d2 = 32; d2 >= 1; d2 >>= 1) t0 += __shfl_xor(t0, d2, 64);
      qkn = t0;
      const float sfq = fmaf(qkc, beff, gf);
      const float svq = fmaf(qkc, bess, gs);
      of_new = fmaf(cfs, svq, sfq);
      os_new = fmaf(csf, sfq, svq);
    }

    float kr1[8], qr1[8];
#pragma unroll
    for (int j = 0; j < 8; ++j) {
      kr1[j] = rdl_(kvA, w * 8 + j);
      qr1[j] = rdl_(qvA, w * 8 + j);
    }

    float ef1 = 0.f, es1 = 0.f, gf1 = 0.f, gs1 = 0.f;
#pragma unroll
    for (int j = 0; j < 8; ++j) {
      float sfv = fmaf(kr[j], beff, Sf[j]);
      float svv = fmaf(kr[j], bess, Ss[j]);
      float tf = fmaf(cfs, svv, sfv);
      float ts = fmaf(csf, sfv, svv);
      ef1 = fmaf(kr1[j], tf, ef1);
      es1 = fmaf(kr1[j], ts, es1);
      gf1 = fmaf(qr1[j], tf, gf1);
      gs1 = fmaf(qr1[j], ts, gs1);
      Sf[j] = tf; Ss[j] = ts;
    }

    alf = d_f; als = d_s;
    if ((t & 7) == 7) {
#pragma unroll
      for (int j = 0; j < 8; ++j) { Sf[j] *= alf; Ss[j] *= als; }
      ef1 *= alf; gf1 *= alf; es1 *= als; gs1 *= als;
      of_new *= alf; os_new *= als;
      alf = 1.f; als = 1.f;
    }

    const int par = t & 1;
    pE[g][par][w][lane] = make_float2(ef1, es1);
    pG[g][par][w][lane] = make_float2(gf1, gs1);
    if (w == 0 && lane == 0) xb[g][par] = make_float4(x1, x2, x3, 0.f);

#pragma unroll
    for (int j = 0; j < 8; ++j) kr[j] = kr1[j];
    kvA = kvB; qvA = qvB; vv = vn; sc = scn; sg4 = sgn; qkc = qkn;
    fdp = fdt; sdp = sdt; fgp = fgt; sgp = sgt;
    ofp = of_new; osp = os_new;
  }

  asm volatile("s_waitcnt lgkmcnt(0)" ::: "memory");
  __builtin_amdgcn_s_barrier();
  if (w == 1) {
    const float4 xv = xb[g][1023 & 1];
    const float Nfd = fmaf(fdp * fdp, Nf, xv.x);
    const float Nsd = fmaf(sdp * sdp, Ns, xv.y);
    const float Cd  = fmaf(fdp * sdp, Cc, xv.z);
    const float NTf = Nfd + 2.f * rf * Cd + rf2 * Nsd;
    const float NTs = Nsd + 2.f * rf * Cd + rf2 * Nfd;
    const float scf = (NTf > 4096.f) ? 64.f * rsqrtf(NTf) : 1.f;
    const float scs = (NTs > 4096.f) ? 64.f * rsqrtf(NTs) : 1.f;
    alf *= scf; als *= scs;
    ob[(size_t)1023 * 1024 + lane] = fgp * alf * ofp + sgp * als * osp;
  }
}

// ---------------------------------------------------------------------------
// Gated RMSNorm + bf16 hi/lo split fused.
// ---------------------------------------------------------------------------
__global__ __launch_bounds__(256) void rms_gate_split(
    const float* __restrict__ o, const float* __restrict__ gsil,
    const float* __restrict__ onw, u16* __restrict__ OH, u16* __restrict__ OL)
{
  int gi = blockIdx.x * 4 + (threadIdx.x >> 6);
  int lane = threadIdx.x & 63;
  size_t idx = (size_t)gi * 64 + lane;
  float x = o[idx];
  float ss = x * x;
#pragma unroll
  for (int d2 = 32; d2 >= 1; d2 >>= 1) ss += __shfl_xor(ss, d2, 64);
  float r = rsqrtf(ss * (1.f / 64.f) + 1e-5f);
  float y = x * r * onw[lane] * gsil[idx];
  u16 h, l;
  split2_(y, h, l);
  OH[idx] = h;
  OL[idx] = l;
}

// ---------------------------------------------------------------------------
// Host launcher
// ---------------------------------------------------------------------------
extern "C" void kernel_launch(void* const* d_in, const int* in_sizes, int n_in,
                              void* d_out, int out_size, void* d_ws, size_t ws_size,
                              hipStream_t stream)
{
  const float* hs  = (const float*)d_in[0];
  const float* Wq  = (const float*)d_in[1];
  const float* bq  = (const float*)d_in[2];
  const float* Wk  = (const float*)d_in[3];
  const float* bk  = (const float*)d_in[4];
  const float* Wv  = (const float*)d_in[5];
  const float* bv  = (const float*)d_in[6];
  const float* Wb  = (const float*)d_in[7];
  const float* bb  = (const float*)d_in[8];
  const float* Wfd = (const float*)d_in[9];
  const float* bfd = (const float*)d_in[10];
  const float* fdb = (const float*)d_in[11];
  const float* Wsd = (const float*)d_in[12];
  const float* bsd = (const float*)d_in[13];
  const float* sdb = (const float*)d_in[14];
  const float* Wfg = (const float*)d_in[15];
  const float* bfg = (const float*)d_in[16];
  const float* Wsg = (const float*)d_in[17];
  const float* bsg = (const float*)d_in[18];
  const float* Wg  = (const float*)d_in[19];
  const float* bg  = (const float*)d_in[20];
  const float* onw = (const float*)d_in[21];
  const float* Wo  = (const float*)d_in[22];
  const float* bo  = (const float*)d_in[23];
  const float* rfx = (const float*)d_in[24];

  float* ws = (float*)d_ws;
  const size_t TWO_M = (size_t)1 << 21;  // 2M floats = B*L*D
  float* q_ws  = ws;
  float* k_ws  = ws + TWO_M;
  float* v_ws  = ws + 2 * TWO_M;
  float* g_ws  = ws + 3 * TWO_M;
  float* o_ws  = ws + 4 * TWO_M;
  float* scl_ws = ws + 5 * TWO_M;            // 262144 floats
  u16*   wt    = (u16*)(ws + 5 * TWO_M + 262144);  // 5 x (1M hi + 1M lo) u16
  u16* hs_hi = (u16*)o_ws;                   // overlays o_ws until scan
  u16* hs_lo = (u16*)(o_ws + TWO_M / 2);
  u16* og_hi = (u16*)v_ws;                   // overlays v_ws after scan
  u16* og_lo = (u16*)(v_ws + TWO_M / 2);

  const size_t WSZ = 1048576;
  u16* WqTh = wt;               u16* WqTl = wt + WSZ;
  u16* WkTh = wt + 2 * WSZ;     u16* WkTl = wt + 3 * WSZ;
  u16* WvTh = wt + 4 * WSZ;     u16* WvTl = wt + 5 * WSZ;
  u16* WgTh = wt + 6 * WSZ;     u16* WgTl = wt + 7 * WSZ;
  u16* WoTh = wt + 8 * WSZ;     u16* WoTl = wt + 9 * WSZ;

  // 0) split hs into bf16 hi/lo
  split_mk<<<2048, 256, 0, stream>>>(hs, hs_hi, hs_lo, (int)(TWO_M / 4));

  // 0b) transpose + split the 5 big weight matrices
  WSplitBatch wb;
  wb.s[0] = { Wq, WqTh, WqTl };
  wb.s[1] = { Wk, WkTh, WkTl };
  wb.s[2] = { Wv, WvTh, WvTl };
  wb.s[3] = { Wg, WgTh, WgTl };
  wb.s[4] = { Wo, WoTh, WoTl };
  splitT<<<dim3(32, 32, 5), 256, 0, stream>>>(wb);

  // 1) big projections via split-bf16 MFMA
  MBatch gb1;
  gb1.s[0] = { WqTh, WqTl, bq, q_ws, 2 };
  gb1.s[1] = { WkTh, WkTl, bk, k_ws, 2 };
  gb1.s[2] = { WvTh, WvTl, bv, v_ws, 2 };
  gb1.s[3] = { WgTh, WgTl, bg, g_ws, 1 };
  gemm_mfma<<<dim3(16, 16, 4), 256, 0, stream>>>(hs_hi, hs_lo, gb1, 2048, 1024, 1024);

  // 2) per-head scalar projections
  scalar_proj<<<256, 256, 0, stream>>>(hs, Wb, bb, Wfd, bfd, fdb, Wsd, bsd, sdb,
                                       Wfg, bfg, Wsg, bsg, scl_ws);

  // 3) pre-normalize q,k
  prenorm<<<16384, 256, 0, stream>>>(q_ws);

  // 4) sequential dual-state delta-rule scan: 2 groups/block, 4 waves/SIMD
  scan_kernel<<<16, 1024, 0, stream>>>(q_ws, k_ws, v_ws, scl_ws, rfx, o_ws);

  // 5) gated RMSNorm fused with bf16 split -> og_hi/og_lo
  rms_gate_split<<<8192, 256, 0, stream>>>(o_ws, g_ws, onw, og_hi, og_lo);

  // 6) output projection via split-bf16 MFMA -> d_out
  MBatch gb2;
  gb2.s[0] = { WoTh, WoTl, bo, (float*)d_out, 0 };
  gb2.s[1] = gb2.s[0]; gb2.s[2] = gb2.s[0]; gb2.s[3] = gb2.s[0];
  gemm_mfma<<<dim3(16, 16, 1), 256, 0, stream>>>(og_hi, og_lo, gb2, 2048, 1024, 1024);
}

// Round 19
// 1381.533 us; speedup vs baseline: 1.4569x; 1.4569x over previous
//
#include <hip/hip_runtime.h>

// ---------------------------------------------------------------------------
// Problem constants: B=2, L=1024, D=1024, H=16, DK=DV=64
// ---------------------------------------------------------------------------

typedef unsigned short u16;
typedef u16  u16x4 __attribute__((ext_vector_type(4)));
typedef short bf16x8 __attribute__((ext_vector_type(8)));
typedef float f32x4 __attribute__((ext_vector_type(4)));

struct MSlot { const u16* Wh; const u16* Wl; const float* bias; float* out; int mode; };
struct MBatch { MSlot s[4]; };
struct WSplitSlot { const float* W; u16* Th; u16* Tl; };
struct WSplitBatch { WSplitSlot s[5]; };

__device__ __forceinline__ float silu_(float x) {
  return x / (1.f + __expf(-x));
}
__device__ __forceinline__ float sigm_(float x) {
  return 1.f / (1.f + __expf(-x));
}
__device__ __forceinline__ float rdl_(float v, int l) {
  return __int_as_float(__builtin_amdgcn_readlane(__float_as_int(v), l));
}
// round-to-nearest-even bf16 split: x ~= hi + lo (each bf16), err ~ x*2^-17
__device__ __forceinline__ void split2_(float x, u16& h, u16& l) {
  unsigned u = __float_as_uint(x);
  unsigned r = (u + 0x7FFFu + ((u >> 16) & 1u)) >> 16;
  h = (u16)r;
  float lo = x - __uint_as_float(r << 16);
  unsigned u2 = __float_as_uint(lo);
  unsigned r2 = (u2 + 0x7FFFu + ((u2 >> 16) & 1u)) >> 16;
  l = (u16)r2;
}

// ---------------------------------------------------------------------------
// split_mk: X[n] f32 -> H[n], L[n] bf16 (hi/lo), float4-vectorized.
// ---------------------------------------------------------------------------
__global__ __launch_bounds__(256) void split_mk(
    const float* __restrict__ X, u16* __restrict__ H, u16* __restrict__ L, int n4)
{
  int i = blockIdx.x * 256 + threadIdx.x;
  if (i >= n4) return;
  float4 x = ((const float4*)X)[i];
  u16 h0, h1, h2, h3, l0, l1, l2, l3;
  split2_(x.x, h0, l0);
  split2_(x.y, h1, l1);
  split2_(x.z, h2, l2);
  split2_(x.w, h3, l3);
  u16x4 h, l;
  h.x = h0; h.y = h1; h.z = h2; h.w = h3;
  l.x = l0; l.y = l1; l.z = l2; l.w = l3;
  ((u16x4*)H)[i] = h;
  ((u16x4*)L)[i] = l;
}

// ---------------------------------------------------------------------------
// splitT: W[1024][1024] f32 -> Th[N][K], Tl[N][K] bf16 (transposed + split).
// ---------------------------------------------------------------------------
__global__ __launch_bounds__(256) void splitT(WSplitBatch wb)
{
  const WSplitSlot sl = wb.s[blockIdx.z];
  __shared__ float tl[32][33];
  const int tid = threadIdx.x;
  const int k0 = blockIdx.x * 32, n0 = blockIdx.y * 32;
  const int c = tid & 31, r8 = tid >> 5;
#pragma unroll
  for (int j = 0; j < 4; ++j) {
    int r = r8 + 8 * j;
    tl[r][c] = sl.W[(size_t)(k0 + r) * 1024 + n0 + c];
  }
  __syncthreads();
#pragma unroll
  for (int j = 0; j < 4; ++j) {
    int nr = r8 + 8 * j;
    float x = tl[c][nr];
    u16 h, l;
    split2_(x, h, l);
    sl.Th[(size_t)(n0 + nr) * 1024 + k0 + c] = h;
    sl.Tl[(size_t)(n0 + nr) * 1024 + k0 + c] = l;
  }
}

// ---------------------------------------------------------------------------
// Split-bf16 MFMA GEMM (r17, passed): register double-buffered fragments.
// ---------------------------------------------------------------------------
__global__ __launch_bounds__(256) void gemm_mfma(
    const u16* __restrict__ Ah, const u16* __restrict__ Al,
    MBatch gb, int M, int N, int K)
{
  const MSlot sl = gb.s[blockIdx.z];
  const int tid = threadIdx.x;
  const int w = tid >> 6, lane = tid & 63;
  const int fm = lane & 15, kg = lane >> 4;
  const int bm = blockIdx.x * 128, bn = blockIdx.y * 64;

  const size_t arow = (size_t)(bm + 32 * w + fm) * K + kg * 8;
  const u16* pa0h = Ah + arow;
  const u16* pa1h = pa0h + 16 * K;
  const u16* pa0l = Al + arow;
  const u16* pa1l = pa0l + 16 * K;
  const size_t brow = (size_t)(bn + fm) * K + kg * 8;
  const u16* pbh = sl.Wh + brow;
  const u16* pbl = sl.Wl + brow;

  f32x4 acc[2][4];
#pragma unroll
  for (int i = 0; i < 2; ++i)
#pragma unroll
    for (int j = 0; j < 4; ++j) acc[i][j] = (f32x4)(0.f);

  bf16x8 a0h = *(const bf16x8*)(pa0h);
  bf16x8 a1h = *(const bf16x8*)(pa1h);
  bf16x8 a0l = *(const bf16x8*)(pa0l);
  bf16x8 a1l = *(const bf16x8*)(pa1l);
  bf16x8 bh[4], bl[4];
#pragma unroll
  for (int c = 0; c < 4; ++c) {
    bh[c] = *(const bf16x8*)(pbh + (size_t)16 * c * K);
    bl[c] = *(const bf16x8*)(pbl + (size_t)16 * c * K);
  }

  for (int ko = 0; ko < K; ko += 32) {
    bf16x8 na0h, na1h, na0l, na1l, nbh[4], nbl[4];
    const int kn = ko + 32;
    if (kn < K) {
      na0h = *(const bf16x8*)(pa0h + kn);
      na1h = *(const bf16x8*)(pa1h + kn);
      na0l = *(const bf16x8*)(pa0l + kn);
      na1l = *(const bf16x8*)(pa1l + kn);
#pragma unroll
      for (int c = 0; c < 4; ++c) {
        nbh[c] = *(const bf16x8*)(pbh + (size_t)16 * c * K + kn);
        nbl[c] = *(const bf16x8*)(pbl + (size_t)16 * c * K + kn);
      }
    }
#pragma unroll
    for (int c = 0; c < 4; ++c) {
      acc[0][c] = __builtin_amdgcn_mfma_f32_16x16x32_bf16(a0h, bh[c], acc[0][c], 0, 0, 0);
      acc[0][c] = __builtin_amdgcn_mfma_f32_16x16x32_bf16(a0l, bh[c], acc[0][c], 0, 0, 0);
      acc[0][c] = __builtin_amdgcn_mfma_f32_16x16x32_bf16(a0h, bl[c], acc[0][c], 0, 0, 0);
      acc[1][c] = __builtin_amdgcn_mfma_f32_16x16x32_bf16(a1h, bh[c], acc[1][c], 0, 0, 0);
      acc[1][c] = __builtin_amdgcn_mfma_f32_16x16x32_bf16(a1l, bh[c], acc[1][c], 0, 0, 0);
      acc[1][c] = __builtin_amdgcn_mfma_f32_16x16x32_bf16(a1h, bl[c], acc[1][c], 0, 0, 0);
    }
    if (kn < K) {
      a0h = na0h; a1h = na1h; a0l = na0l; a1l = na1l;
#pragma unroll
      for (int c = 0; c < 4; ++c) { bh[c] = nbh[c]; bl[c] = nbl[c]; }
    }
  }

  const float* bias = sl.bias;
  float* out = sl.out;
  const int mode = sl.mode;
#pragma unroll
  for (int rt = 0; rt < 2; ++rt) {
#pragma unroll
    for (int c = 0; c < 4; ++c) {
      f32x4 v = acc[rt][c];
      const int n = bn + 16 * c + fm;
      const float bsv = bias[n];
#pragma unroll
      for (int r = 0; r < 4; ++r) {
        int m = bm + 32 * w + 16 * rt + kg * 4 + r;
        float cc = v[r] + bsv;
        if (mode >= 1) cc = silu_(cc);
        if (mode == 2) {
          int h = n >> 6, d = n & 63;
          int b = m >> 10, l = m & 1023;
          out[(((size_t)(b * 16 + h)) * 1024 + l) * 64 + d] = cc;
        } else {
          out[(size_t)m * N + n] = cc;
        }
      }
    }
  }
}

// ---------------------------------------------------------------------------
// Scalar projections: LDS-tiled (8 hs rows/block), packed scl[bh][t][8]
// ---------------------------------------------------------------------------
__global__ __launch_bounds__(256) void scalar_proj(
    const float* __restrict__ hs,
    const float* __restrict__ Wb,  const float* __restrict__ bb,
    const float* __restrict__ Wfd, const float* __restrict__ bfd, const float* __restrict__ fdb,
    const float* __restrict__ Wsd, const float* __restrict__ bsd, const float* __restrict__ sdb,
    const float* __restrict__ Wfg, const float* __restrict__ bfg,
    const float* __restrict__ Wsg, const float* __restrict__ bsg,
    float* __restrict__ scl)
{
  __shared__ float hl[8][1028];
  const int tid = threadIdx.x;
  const int m0 = blockIdx.x * 8;

#pragma unroll
  for (int i = 0; i < 8; ++i) {
    int f = tid + 256 * i;
    int r = f >> 8;
    int c4 = f & 255;
    float4 v = *(const float4*)&hs[(size_t)(m0 + r) * 1024 + c4 * 4];
    *(float4*)&hl[r][c4 * 4] = v;
  }
  __syncthreads();

  for (int c = 0; c < 3; ++c) {
    int o = tid + 256 * c;
    if (o >= 640) break;
    int ml = o / 80;
    int cc = o - ml * 80;
    int type = cc >> 4;
    int h = cc & 15;
    const float* W; const float* bias; float extra = 0.f;
    switch (type) {
      case 0:  W = Wb;  bias = bb;  break;
      case 1:  W = Wfd; bias = bfd; extra = fdb[h]; break;
      case 2:  W = Wsd; bias = bsd; extra = sdb[h]; break;
      case 3:  W = Wfg; bias = bfg; break;
      default: W = Wsg; bias = bsg; break;
    }
    float s = 0.f;
    for (int k = 0; k < 1024; k += 4) {
      float4 hv = *(const float4*)&hl[ml][k];
      s = fmaf(hv.x, W[(k + 0) * 16 + h], s);
      s = fmaf(hv.y, W[(k + 1) * 16 + h], s);
      s = fmaf(hv.z, W[(k + 2) * 16 + h], s);
      s = fmaf(hv.w, W[(k + 3) * 16 + h], s);
    }
    s += bias[h] + extra;
    int m = m0 + ml;
    int b = m >> 10, l = m & 1023;
    scl[((size_t)((b * 16 + h) * 1024 + l)) * 8 + type] = sigm_(s);
  }
}

// ---------------------------------------------------------------------------
// Pre-normalize q and k in place: x *= rsqrt(sum_64(x^2)+1e-6).
// ---------------------------------------------------------------------------
__global__ __launch_bounds__(256) void prenorm(float* __restrict__ p)
{
  int wid = blockIdx.x * 4 + (threadIdx.x >> 6);
  int lane = threadIdx.x & 63;
  size_t idx = (size_t)wid * 64 + lane;
  float x = p[idx];
  float ss = x * x;
#pragma unroll
  for (int d2 = 32; d2 >= 1; d2 >>= 1) ss += __shfl_xor(ss, d2, 64);
  p[idx] = x * rsqrtf(ss + 1e-6f);
}

// ---------------------------------------------------------------------------
// Sequential scan v13 (REVERTED to r13/r17 config: 32 blocks x 512 threads,
// 8 waves x 8 rows per (b,h), one raw barrier/step, deferred cap, wave-
// specialized reduces, refold every 8 steps. 1094us, passed, proven best.
// r18's 2-groups/block 4-waves/SIMD variant regressed to 1723us: the
// shared barrier couples two groups -> each step waits on the slower of
// 16 waves; coupling skew exceeded the latency-hiding gain.)
// ---------------------------------------------------------------------------
__global__ __launch_bounds__(512) void scan_kernel(
    const float* __restrict__ qg, const float* __restrict__ kg, const float* __restrict__ vg,
    const float* __restrict__ scl, const float* __restrict__ rfx, float* __restrict__ og)
{
  const int bh = blockIdx.x;     // 0..31
  const int tid = threadIdx.x;
  const int lane = tid & 63;     // column index
  const int w = tid >> 6;        // wave id 0..7: rows [8w, 8w+8)
  const float rf = rfx[0];
  const float rf2 = rf * rf;

  __shared__ float2 pE[2][8][64];
  __shared__ float2 pG[2][8][64];
  __shared__ float4 xb[2];

  float Sf[8], Ss[8];
#pragma unroll
  for (int j = 0; j < 8; ++j) { Sf[j] = 0.f; Ss[j] = 0.f; }

  const float* kb = kg + (size_t)bh * 65536;
  const float* qb = qg + (size_t)bh * 65536;
  const float* vb = vg + (size_t)bh * 65536;
  const float* sb = scl + (size_t)bh * 8192;
  const int b = bh >> 4, h = bh & 15;
  float* ob = og + (size_t)b * (1024 * 1024) + h * 64;

  float kv0 = kb[lane], qv0 = qb[lane];
  float kvA = kb[64 + lane], qvA = qb[64 + lane];
  float vv = vb[lane];
  float4 sc = *(const float4*)&sb[0];
  float sg4 = sb[4];

  float kr[8];
#pragma unroll
  for (int j = 0; j < 8; ++j) kr[j] = rdl_(kv0, w * 8 + j);

  float qkc = 0.f;
  if (w == 1) {
    float t0 = kv0 * qv0;
#pragma unroll
    for (int d2 = 32; d2 >= 1; d2 >>= 1) t0 += __shfl_xor(t0, d2, 64);
    qkc = t0;
  }

  float alf = 1.f, als = 1.f;
  float Nf = 0.f, Ns = 0.f, Cc = 0.f;
  float fdp = 1.f, sdp = 1.f;
  float fgp = 0.f, sgp = 0.f;
  float ofp = 0.f, osp = 0.f;
  float ef = 0.f, es = 0.f, gf = 0.f, gs = 0.f;

  for (int t = 0; t < 1024; ++t) {
    const int t1 = (t + 1) & 1023;
    const int t2 = (t + 2) & 1023;

    if (t > 0) {
      asm volatile("s_waitcnt lgkmcnt(0)" ::: "memory");
      __builtin_amdgcn_s_barrier();
    }

    const float kvB = kb[t2 * 64 + lane];
    const float qvB = qb[t2 * 64 + lane];
    const float vn  = vb[t1 * 64 + lane];
    const float4 scn = *(const float4*)&sb[(size_t)t1 * 8];
    const float sgn = sb[(size_t)t1 * 8 + 4];

    if (t > 0) {
      const int pr = (t - 1) & 1;
      float2 e0 = pE[pr][0][lane], e1 = pE[pr][1][lane];
      float2 e2 = pE[pr][2][lane], e3 = pE[pr][3][lane];
      float2 e4 = pE[pr][4][lane], e5 = pE[pr][5][lane];
      float2 e6 = pE[pr][6][lane], e7 = pE[pr][7][lane];
      float2 g0 = pG[pr][0][lane], g1 = pG[pr][1][lane];
      float2 g2 = pG[pr][2][lane], g3 = pG[pr][3][lane];
      float2 g4 = pG[pr][4][lane], g5 = pG[pr][5][lane];
      float2 g6 = pG[pr][6][lane], g7 = pG[pr][7][lane];
      ef = ((e0.x + e1.x) + (e2.x + e3.x)) + ((e4.x + e5.x) + (e6.x + e7.x));
      es = ((e0.y + e1.y) + (e2.y + e3.y)) + ((e4.y + e5.y) + (e6.y + e7.y));
      gf = ((g0.x + g1.x) + (g2.x + g3.x)) + ((g4.x + g5.x) + (g6.x + g7.x));
      gs = ((g0.y + g1.y) + (g2.y + g3.y)) + ((g4.y + g5.y) + (g6.y + g7.y));
      const float4 xv = xb[pr];
      const float Nfd = fmaf(fdp * fdp, Nf, xv.x);
      const float Nsd = fmaf(sdp * sdp, Ns, xv.y);
      const float Cd  = fmaf(fdp * sdp, Cc, xv.z);
      const float NTf = Nfd + 2.f * rf * Cd + rf2 * Nsd;
      const float NTs = Nsd + 2.f * rf * Cd + rf2 * Nfd;
      const float CT  = (1.f + rf2) * Cd + rf * (Nfd + Nsd);
      const bool capf = NTf > 4096.f;
      const bool caps = NTs > 4096.f;
      const float scf = capf ? 64.f * rsqrtf(NTf) : 1.f;
      const float scs = caps ? 64.f * rsqrtf(NTs) : 1.f;
      Nf = capf ? 4096.f : NTf;
      Ns = caps ? 4096.f : NTs;
      Cc = scf * scs * CT;
      alf *= scf; als *= scs;
      if (w == 1)
        ob[(size_t)(t - 1) * 1024 + lane] = fgp * alf * ofp + sgp * als * osp;
    }

    const float bt = sc.x, fdt = sc.y, sdt = sc.z, fgt = sc.w, sgt = sg4;

    const float d_f = alf * fdt, d_s = als * sdt;
    const float EF = d_f * ef, ES = d_s * es;
    const float errf = vv - EF, errs = vv - ES;
    const float rdf = 1.f / d_f, rds = 1.f / d_s;
    const float beff = bt * errf * rdf;
    const float bess = bt * errs * rds;
    const float cfs = rf * d_s * rdf;
    const float csf = rf * d_f * rds;

    float x1 = 0.f, x2 = 0.f, x3 = 0.f;
    if (w == 0) {
      x1 = bt * errf * fmaf(bt, errf, 2.f * EF);
      x2 = bt * errs * fmaf(bt, errs, 2.f * ES);
      x3 = bt * (fmaf(bt, errf * errs, errs * EF) + errf * ES);
#pragma unroll
      for (int d2 = 32; d2 >= 1; d2 >>= 1) {
        x1 += __shfl_xor(x1, d2, 64);
        x2 += __shfl_xor(x2, d2, 64);
        x3 += __shfl_xor(x3, d2, 64);
      }
    }

    float qkn = 0.f, of_new = 0.f, os_new = 0.f;
    if (w == 1) {
      float t0 = kvA * qvA;
#pragma unroll
      for (int d2 = 32; d2 >= 1; d2 >>= 1) t0 += __shfl_xor(t0, d2, 64);
      qkn = t0;
      const float sfq = fmaf(qkc, beff, gf);
      const float svq = fmaf(qkc, bess, gs);
      of_new = fmaf(cfs, svq, sfq);
      os_new = fmaf(csf, sfq, svq);
    }

    float kr1[8], qr1[8];
#pragma unroll
    for (int j = 0; j < 8; ++j) {
      kr1[j] = rdl_(kvA, w * 8 + j);
      qr1[j] = rdl_(qvA, w * 8 + j);
    }

    float ef1 = 0.f, es1 = 0.f, gf1 = 0.f, gs1 = 0.f;
#pragma unroll
    for (int j = 0; j < 8; ++j) {
      float sfv = fmaf(kr[j], beff, Sf[j]);
      float svv = fmaf(kr[j], bess, Ss[j]);
      float tf = fmaf(cfs, svv, sfv);
      float ts = fmaf(csf, sfv, svv);
      ef1 = fmaf(kr1[j], tf, ef1);
      es1 = fmaf(kr1[j], ts, es1);
      gf1 = fmaf(qr1[j], tf, gf1);
      gs1 = fmaf(qr1[j], ts, gs1);
      Sf[j] = tf; Ss[j] = ts;
    }

    alf = d_f; als = d_s;
    if ((t & 7) == 7) {
#pragma unroll
      for (int j = 0; j < 8; ++j) { Sf[j] *= alf; Ss[j] *= als; }
      ef1 *= alf; gf1 *= alf; es1 *= als; gs1 *= als;
      of_new *= alf; os_new *= als;
      alf = 1.f; als = 1.f;
    }

    const int par = t & 1;
    pE[par][w][lane] = make_float2(ef1, es1);
    pG[par][w][lane] = make_float2(gf1, gs1);
    if (w == 0 && lane == 0) xb[par] = make_float4(x1, x2, x3, 0.f);

#pragma unroll
    for (int j = 0; j < 8; ++j) kr[j] = kr1[j];
    kvA = kvB; qvA = qvB; vv = vn; sc = scn; sg4 = sgn; qkc = qkn;
    fdp = fdt; sdp = sdt; fgp = fgt; sgp = sgt;
    ofp = of_new; osp = os_new;
  }

  asm volatile("s_waitcnt lgkmcnt(0)" ::: "memory");
  __builtin_amdgcn_s_barrier();
  if (w == 1) {
    const float4 xv = xb[1023 & 1];
    const float Nfd = fmaf(fdp * fdp, Nf, xv.x);
    const float Nsd = fmaf(sdp * sdp, Ns, xv.y);
    const float Cd  = fmaf(fdp * sdp, Cc, xv.z);
    const float NTf = Nfd + 2.f * rf * Cd + rf2 * Nsd;
    const float NTs = Nsd + 2.f * rf * Cd + rf2 * Nfd;
    const float scf = (NTf > 4096.f) ? 64.f * rsqrtf(NTf) : 1.f;
    const float scs = (NTs > 4096.f) ? 64.f * rsqrtf(NTs) : 1.f;
    alf *= scf; als *= scs;
    ob[(size_t)1023 * 1024 + lane] = fgp * alf * ofp + sgp * als * osp;
  }
}

// ---------------------------------------------------------------------------
// Gated RMSNorm + bf16 hi/lo split fused.
// ---------------------------------------------------------------------------
__global__ __launch_bounds__(256) void rms_gate_split(
    const float* __restrict__ o, const float* __restrict__ gsil,
    const float* __restrict__ onw, u16* __restrict__ OH, u16* __restrict__ OL)
{
  int gi = blockIdx.x * 4 + (threadIdx.x >> 6);
  int lane = threadIdx.x & 63;
  size_t idx = (size_t)gi * 64 + lane;
  float x = o[idx];
  float ss = x * x;
#pragma unroll
  for (int d2 = 32; d2 >= 1; d2 >>= 1) ss += __shfl_xor(ss, d2, 64);
  float r = rsqrtf(ss * (1.f / 64.f) + 1e-5f);
  float y = x * r * onw[lane] * gsil[idx];
  u16 h, l;
  split2_(y, h, l);
  OH[idx] = h;
  OL[idx] = l;
}

// ---------------------------------------------------------------------------
// Host launcher
// ---------------------------------------------------------------------------
extern "C" void kernel_launch(void* const* d_in, const int* in_sizes, int n_in,
                              void* d_out, int out_size, void* d_ws, size_t ws_size,
                              hipStream_t stream)
{
  const float* hs  = (const float*)d_in[0];
  const float* Wq  = (const float*)d_in[1];
  const float* bq  = (const float*)d_in[2];
  const float* Wk  = (const float*)d_in[3];
  const float* bk  = (const float*)d_in[4];
  const float* Wv  = (const float*)d_in[5];
  const float* bv  = (const float*)d_in[6];
  const float* Wb  = (const float*)d_in[7];
  const float* bb  = (const float*)d_in[8];
  const float* Wfd = (const float*)d_in[9];
  const float* bfd = (const float*)d_in[10];
  const float* fdb = (const float*)d_in[11];
  const float* Wsd = (const float*)d_in[12];
  const float* bsd = (const float*)d_in[13];
  const float* sdb = (const float*)d_in[14];
  const float* Wfg = (const float*)d_in[15];
  const float* bfg = (const float*)d_in[16];
  const float* Wsg = (const float*)d_in[17];
  const float* bsg = (const float*)d_in[18];
  const float* Wg  = (const float*)d_in[19];
  const float* bg  = (const float*)d_in[20];
  const float* onw = (const float*)d_in[21];
  const float* Wo  = (const float*)d_in[22];
  const float* bo  = (const float*)d_in[23];
  const float* rfx = (const float*)d_in[24];

  float* ws = (float*)d_ws;
  const size_t TWO_M = (size_t)1 << 21;  // 2M floats = B*L*D
  float* q_ws  = ws;
  float* k_ws  = ws + TWO_M;
  float* v_ws  = ws + 2 * TWO_M;
  float* g_ws  = ws + 3 * TWO_M;
  float* o_ws  = ws + 4 * TWO_M;
  float* scl_ws = ws + 5 * TWO_M;            // 262144 floats
  u16*   wt    = (u16*)(ws + 5 * TWO_M + 262144);  // 5 x (1M hi + 1M lo) u16
  u16* hs_hi = (u16*)o_ws;                   // overlays o_ws until scan
  u16* hs_lo = (u16*)(o_ws + TWO_M / 2);
  u16* og_hi = (u16*)v_ws;                   // overlays v_ws after scan
  u16* og_lo = (u16*)(v_ws + TWO_M / 2);

  const size_t WSZ = 1048576;
  u16* WqTh = wt;               u16* WqTl = wt + WSZ;
  u16* WkTh = wt + 2 * WSZ;     u16* WkTl = wt + 3 * WSZ;
  u16* WvTh = wt + 4 * WSZ;     u16* WvTl = wt + 5 * WSZ;
  u16* WgTh = wt + 6 * WSZ;     u16* WgTl = wt + 7 * WSZ;
  u16* WoTh = wt + 8 * WSZ;     u16* WoTl = wt + 9 * WSZ;

  // 0) split hs into bf16 hi/lo
  split_mk<<<2048, 256, 0, stream>>>(hs, hs_hi, hs_lo, (int)(TWO_M / 4));

  // 0b) transpose + split the 5 big weight matrices
  WSplitBatch wb;
  wb.s[0] = { Wq, WqTh, WqTl };
  wb.s[1] = { Wk, WkTh, WkTl };
  wb.s[2] = { Wv, WvTh, WvTl };
  wb.s[3] = { Wg, WgTh, WgTl };
  wb.s[4] = { Wo, WoTh, WoTl };
  splitT<<<dim3(32, 32, 5), 256, 0, stream>>>(wb);

  // 1) big projections via split-bf16 MFMA
  MBatch gb1;
  gb1.s[0] = { WqTh, WqTl, bq, q_ws, 2 };
  gb1.s[1] = { WkTh, WkTl, bk, k_ws, 2 };
  gb1.s[2] = { WvTh, WvTl, bv, v_ws, 2 };
  gb1.s[3] = { WgTh, WgTl, bg, g_ws, 1 };
  gemm_mfma<<<dim3(16, 16, 4), 256, 0, stream>>>(hs_hi, hs_lo, gb1, 2048, 1024, 1024);

  // 2) per-head scalar projections
  scalar_proj<<<256, 256, 0, stream>>>(hs, Wb, bb, Wfd, bfd, fdb, Wsd, bsd, sdb,
                                       Wfg, bfg, Wsg, bsg, scl_ws);

  // 3) pre-normalize q,k
  prenorm<<<16384, 256, 0, stream>>>(q_ws);

  // 4) sequential dual-state delta-rule scan (r13 proven config)
  scan_kernel<<<32, 512, 0, stream>>>(q_ws, k_ws, v_ws, scl_ws, rfx, o_ws);

  // 5) gated RMSNorm fused with bf16 split -> og_hi/og_lo
  rms_gate_split<<<8192, 256, 0, stream>>>(o_ws, g_ws, onw, og_hi, og_lo);

  // 6) output projection via split-bf16 MFMA -> d_out
  MBatch gb2;
  gb2.s[0] = { WoTh, WoTl, bo, (float*)d_out, 0 };
  gb2.s[1] = gb2.s[0]; gb2.s[2] = gb2.s[0]; gb2.s[3] = gb2.s[0];
  gemm_mfma<<<dim3(16, 16, 1), 256, 0, stream>>>(og_hi, og_lo, gb2, 2048, 1024, 1024);
}